// Round 3
// baseline (154.449 us; speedup 1.0000x reference)
//
#include <hip/hip_runtime.h>

// YOLO-style loss: y_pred (1024,28,28,30) f32, y_true (1024,28,28,5) f32 -> scalar f32.
// DRAM floor: 112.4 MB read @ ~6.3 TB/s ~= 18 us. Harness poison fills (2 x 385 MB ~= 113 us
// at 85% write BW) dominate dur_us and are not controllable from kernel_launch.
// R5 barrier-free wave-private LDS staging (16 waves/CU): dur 152.
// R6 global_load_lds + dbuf + inline vmcnt(14): dur 153. R7 + opaque-asm ds_reads: dur 154.
//   Post-mortem R6/R7: with pending global_load_lds (VMEM that writes LDS), LLVM's
//   waitcnt pass conservatively legalizes ANY potential LDS reader -- including an
//   opaque inline-asm block -- with its own s_waitcnt vmcnt(0). The prefetch is
//   drained every iteration no matter what we write. The DMA path cannot be
//   software-pipelined from HIP source here. R6/R7 also halved resident waves
//   (8/CU vs R5's 16/CU) -> slightly WORSE than R5 when the pipeline collapsed.
// R8 (this): T14 reg-staged async split, NO global_load_lds, NO inline asm.
//   Phase A: issue next tile's loads into VGPRs (7x dwordx4 + 1x dwordx2 pred
//            coalesced, 5x b32 y_true per-lane). Registers, not LDS -> the
//            waitcnt pass has nothing to legalize against the ds_reads.
//   Phase B: compute current tile from wave-private LDS (15x ds_read_b64/lane).
//   Phase C: ds_write staged regs -> other buffer; compiler inserts the
//            s_waitcnt vmcnt(0) HERE (first reg use) = after compute. HBM
//            latency hides under phase B. sched_barrier(0) fences keep the
//            scheduler from sinking phase C into phase B.
//   Slab = pred only (2 x 7680 B/wave) -> 5 blocks/CU, 10 waves/CU; in-flight
//   ~90 KB/CU > ~72 KB Little's-law need at 6.3 TB/s. Barrier-free throughout.

#define S_GRID 28
#define N_CELLS (1024 * S_GRID * S_GRID)     // 802816
#define CPW 64                               // cells per wave-tile
#define N_TILES (N_CELLS / CPW)              // 12544
#define WPB 2                                // waves per block
#define BLOCK (WPB * 64)                     // 128
#define NBLOCKS 1280                         // 5 resident blocks/CU * 256 CU
#define NWAVES (NBLOCKS * WPB)               // 2560 persistent waves
#define PRED_FLOATS (CPW * 30)               // 1920 floats = 7680 B per (wave,buf)

typedef float v4f __attribute__((ext_vector_type(4)));
typedef float v2f __attribute__((ext_vector_type(2)));

__device__ __forceinline__ float iou_calc(float bx, float by, float bw, float bh,
                                          float tx, float ty, float tw, float th,
                                          float gi, float gj) {
    float acx = (gj + bx) * 8.0f;
    float acy = (gi + by) * 8.0f;
    float aw  = bw * 224.0f;
    float ah  = bh * 224.0f;
    float ax1 = acx - aw * 0.5f, ax2 = acx + aw * 0.5f;
    float ay1 = acy - ah * 0.5f, ay2 = acy + ah * 0.5f;
    float bcx = (gj + tx) * 8.0f;
    float bcy = (gi + ty) * 8.0f;
    float btw = tw * 224.0f;
    float bth = th * 224.0f;
    float bx1 = bcx - btw * 0.5f, bx2 = bcx + btw * 0.5f;
    float by1 = bcy - bth * 0.5f, by2 = bcy + bth * 0.5f;

    float iw = fmaxf(fminf(ax2, bx2) - fmaxf(ax1, bx1), 0.0f);
    float ih = fmaxf(fminf(ay2, by2) - fmaxf(ay1, by1), 0.0f);
    float inter = iw * ih;
    float area_a = fmaxf(ax2 - ax1, 0.0f) * fmaxf(ay2 - ay1, 0.0f);
    float area_b = fmaxf(bx2 - bx1, 0.0f) * fmaxf(by2 - by1, 0.0f);
    return inter / (area_a + area_b - inter + 1e-12f);
}

__global__ __launch_bounds__(BLOCK, 2) void yolo_loss_kernel(const float* __restrict__ yp,
                                                             const float* __restrict__ yt,
                                                             float* __restrict__ partials) {
    // wave-private double-buffered pred slabs, raw global layout
    __shared__ __align__(16) float lds[WPB][2][PRED_FLOATS];   // 30720 B/block

    int tid  = threadIdx.x;
    int lane = tid & 63;
    int wave = tid >> 6;
    int gwave = blockIdx.x * WPB + wave;

    float acc = 0.0f;
    int cur = 0;

    // staging registers
    v4f a0, a1, a2, a3, a4, a5, a6;   // pred floats 0..1791 (lane-major float4)
    v2f a7;                           // pred floats 1792..1919 (lane-major float2)
    float b0, b1, b2, b3, b4;         // next tile's y_true (own cell)
    float tc, tx, ty, tw, th;         // current tile's y_true (own cell)

    // ---- prologue: stage first tile (every wave has >=1: NWAVES <= N_TILES) ----
    {
        const v4f* g4 = (const v4f*)(yp + (size_t)gwave * PRED_FLOATS);
        a0 = g4[0 * 64 + lane]; a1 = g4[1 * 64 + lane]; a2 = g4[2 * 64 + lane];
        a3 = g4[3 * 64 + lane]; a4 = g4[4 * 64 + lane]; a5 = g4[5 * 64 + lane];
        a6 = g4[6 * 64 + lane];
        a7 = ((const v2f*)(yp + (size_t)gwave * PRED_FLOATS + 1792))[lane];
        const float* gt = yt + (size_t)(gwave * CPW + lane) * 5;
        b0 = gt[0]; b1 = gt[1]; b2 = gt[2]; b3 = gt[3]; b4 = gt[4];

        v4f* s4 = (v4f*)lds[wave][0];
        s4[0 * 64 + lane] = a0; s4[1 * 64 + lane] = a1; s4[2 * 64 + lane] = a2;
        s4[3 * 64 + lane] = a3; s4[4 * 64 + lane] = a4; s4[5 * 64 + lane] = a5;
        s4[6 * 64 + lane] = a6;
        ((v2f*)(lds[wave][0] + 1792))[lane] = a7;
        tc = b0; tx = b1; ty = b2; tw = b3; th = b4;
    }

    for (int t = gwave; t < N_TILES; t += NWAVES) {
        int tn = t + NWAVES;
        bool more = (tn < N_TILES);            // wave-uniform

        // ---- phase A: issue next tile's loads into registers ----
        if (more) {
            const v4f* g4 = (const v4f*)(yp + (size_t)tn * PRED_FLOATS);
            a0 = g4[0 * 64 + lane]; a1 = g4[1 * 64 + lane]; a2 = g4[2 * 64 + lane];
            a3 = g4[3 * 64 + lane]; a4 = g4[4 * 64 + lane]; a5 = g4[5 * 64 + lane];
            a6 = g4[6 * 64 + lane];
            a7 = ((const v2f*)(yp + (size_t)tn * PRED_FLOATS + 1792))[lane];
            const float* gt = yt + (size_t)(tn * CPW + lane) * 5;
            b0 = gt[0]; b1 = gt[1]; b2 = gt[2]; b3 = gt[3]; b4 = gt[4];
        }
        __builtin_amdgcn_sched_barrier(0);

        // ---- phase B: compute current tile from LDS (DS + VALU only) ----
        const float* cp = lds[wave][cur] + lane * 30;
        float pr[30];
#pragma unroll
        for (int k = 0; k < 15; ++k) {
            v2f q = *(const v2f*)(cp + 2 * k);     // ds_read_b64, 8-aligned
            pr[2 * k]     = q.x;
            pr[2 * k + 1] = q.y;
        }

        int cell = t * CPW + lane;
        int ij = cell % (S_GRID * S_GRID);
        float gi = (float)(ij / S_GRID);
        float gj = (float)(ij % S_GRID);

        float iou0 = iou_calc(pr[0], pr[1], pr[2], pr[3], tx, ty, tw, th, gi, gj);
        float iou1 = iou_calc(pr[5], pr[6], pr[7], pr[8], tx, ty, tw, th, gi, gj);
        bool choose1 = !(iou0 > iou1);

        float conf_pred = choose1 ? pr[9] : pr[4];
        float conf_true = choose1 ? iou1 : iou0;
        float xp  = choose1 ? pr[5] : pr[0];
        float ypv = choose1 ? pr[6] : pr[1];

        float dcf = conf_pred - conf_true;
        float d0 = xp - tx, d1 = ypv - ty;

        int cls = (int)tc - 1;   // -1 => one-hot all zeros
        float lcls = 0.0f;
#pragma unroll
        for (int k = 0; k < 20; ++k) {
            float oh = (k == cls) ? 1.0f : 0.0f;
            float d = pr[10 + k] - oh;
            lcls += d * d;
        }

        float obj_loss   = dcf * dcf + 5.0f * (d0 * d0 + d1 * d1) + lcls;
        float noobj_loss = 0.5f * (pr[4] * pr[4] + pr[9] * pr[9]);
        acc += (tc != 0.0f) ? obj_loss : noobj_loss;

        __builtin_amdgcn_sched_barrier(0);

        // ---- phase C: commit staged regs (compiler emits vmcnt(0) here, after
        // compute -- HBM latency was hidden under phase B) ----
        if (more) {
            float* nb = lds[wave][cur ^ 1];
            v4f* s4 = (v4f*)nb;
            s4[0 * 64 + lane] = a0; s4[1 * 64 + lane] = a1; s4[2 * 64 + lane] = a2;
            s4[3 * 64 + lane] = a3; s4[4 * 64 + lane] = a4; s4[5 * 64 + lane] = a5;
            s4[6 * 64 + lane] = a6;
            ((v2f*)(nb + 1792))[lane] = a7;
            tc = b0; tx = b1; ty = b2; tw = b3; th = b4;
        }
        cur ^= 1;
    }

    // one wave-local reduction at the end; one partial per wave, NO barrier
#pragma unroll
    for (int off = 32; off > 0; off >>= 1) {
        acc += __shfl_down(acc, off, 64);
    }
    if (lane == 0) partials[gwave] = acc;
}

__global__ __launch_bounds__(256) void reduce_kernel(const float* __restrict__ partials,
                                                     float* __restrict__ out) {
    int tid = threadIdx.x;
    float s = 0.0f;
#pragma unroll
    for (int k = 0; k < 10; ++k) {           // 10 * 256 = 2560 exact
        s += partials[k * 256 + tid];
    }
#pragma unroll
    for (int off = 32; off > 0; off >>= 1) {
        s += __shfl_down(s, off, 64);
    }
    __shared__ float wsum[4];
    int lane = tid & 63;
    int wid  = tid >> 6;
    if (lane == 0) wsum[wid] = s;
    __syncthreads();
    if (tid == 0) {
        out[0] = (wsum[0] + wsum[1] + wsum[2] + wsum[3]) * (1.0f / 1024.0f);
    }
}

extern "C" void kernel_launch(void* const* d_in, const int* in_sizes, int n_in,
                              void* d_out, int out_size, void* d_ws, size_t ws_size,
                              hipStream_t stream) {
    const float* y_pred = (const float*)d_in[0];
    const float* y_true = (const float*)d_in[1];
    float* out = (float*)d_out;
    float* partials = (float*)d_ws;   // 2560 floats, fully overwritten each call

    yolo_loss_kernel<<<NBLOCKS, BLOCK, 0, stream>>>(y_pred, y_true, partials);
    reduce_kernel<<<1, 256, 0, stream>>>(partials, out);
}